// Round 11
// baseline (283.931 us; speedup 1.0000x reference)
//
#include <hip/hip_runtime.h>
#include <math.h>

#define DIMN 1536
#define NHEAD 12
#define HDIM 128
#define SLEN 2048
#define EPSV 1e-6f

typedef __attribute__((ext_vector_type(8))) short short8;
typedef __attribute__((ext_vector_type(4))) short short4v;
typedef __attribute__((ext_vector_type(4))) float f32x4;

typedef __attribute__((address_space(1))) const void gvoid_t;
typedef __attribute__((address_space(3))) void lvoid_t;

__device__ __forceinline__ void gload_lds16(const void* g, void* l) {
    __builtin_amdgcn_global_load_lds((gvoid_t*)g, (lvoid_t*)l, 16, 0, 0);
}

__device__ inline short to_bf16(float f) {
    union { float f; unsigned u; } v; v.f = f;
    unsigned r = (v.u + 0x7FFFu + ((v.u >> 16) & 1u)) >> 16;
    return (short)r;
}
__device__ inline float bf_to_f(short h) {
    union { unsigned u; float f; } v;
    v.u = ((unsigned)(unsigned short)h) << 16;
    return v.f;
}

// 8-chunk XOR swizzle: spreads fragment ds_read_b128 across all 32 banks
// (2 rows/bank-pair = free per m136); global side stays 128B-coalesced.
__device__ __forceinline__ int swz8(int row, int c) {
    return c ^ (row & 7);
}

// ---------------------------------------------------------------------------
// Cast 5 fp32 tensors to bf16 (x + 4 weights), one launch.
// ---------------------------------------------------------------------------
__global__ __launch_bounds__(256)
void cast5(const float* s0, const float* s1, const float* s2,
           const float* s3, const float* s4,
           short* d0, short* d1, short* d2, short* d3, short* d4,
           int n0, int nw)
{
    const float* s; short* d; int n;
    switch (blockIdx.y) {
        case 0: s = s0; d = d0; n = n0; break;
        case 1: s = s1; d = d1; n = nw; break;
        case 2: s = s2; d = d2; n = nw; break;
        case 3: s = s3; d = d3; n = nw; break;
        default: s = s4; d = d4; n = nw; break;
    }
    int idx = (blockIdx.x * 256 + threadIdx.x) * 8;
    if (idx >= n) return;
    float4 a = *(const float4*)(s + idx);
    float4 b = *(const float4*)(s + idx + 4);
    short8 r;
    r[0] = to_bf16(a.x); r[1] = to_bf16(a.y); r[2] = to_bf16(a.z); r[3] = to_bf16(a.w);
    r[4] = to_bf16(b.x); r[5] = to_bf16(b.y); r[6] = to_bf16(b.z); r[7] = to_bf16(b.w);
    *(short8*)(d + idx) = r;
}

// ---------------------------------------------------------------------------
// BK=64 MFMA GEMM core: 128x128 tile, 24 K-iters, 32 MFMA per barrier pair,
// global_load_lds w=16 staging, 8-chunk XOR swizzle. LDS 32 KB.
// ---------------------------------------------------------------------------
__device__ __forceinline__ void gemm_mainloop(const short* __restrict__ A,
    const short* __restrict__ W, int m0, int n0, int K,
    short* As, short* Bs, f32x4 (&acc)[4][4])
{
    const int tid = threadIdx.x;
    const int wave = tid >> 6, lane = tid & 63;
    const int quad = lane >> 4, col = lane & 15;
    const int wm = wave >> 1, wn = wave & 1;
    const int sr = tid >> 3;          // 0..31: row within a 32-row group
    const int sc = tid & 7;           // chunk slot 0..7

    for (int kt = 0; kt < K; kt += 64) {
        __syncthreads();
        #pragma unroll
        for (int i = 0; i < 4; ++i) {
            const int row = i * 32 + sr;
            const int c = swz8(row, sc);
            gload_lds16(A + (size_t)(m0 + row) * K + kt + c * 8, As + i * 2048 + tid * 8);
        }
        #pragma unroll
        for (int i = 0; i < 4; ++i) {
            const int row = i * 32 + sr;
            const int c = swz8(row, sc);
            gload_lds16(W + (size_t)(n0 + row) * K + kt + c * 8, Bs + i * 2048 + tid * 8);
        }
        __syncthreads();

        #pragma unroll
        for (int kb = 0; kb < 2; ++kb) {
            short8 af[4], bf[4];
            #pragma unroll
            for (int mt = 0; mt < 4; ++mt) {
                const int row = wm * 64 + mt * 16 + col;
                af[mt] = *(const short8*)&As[row * 64 + swz8(row, kb * 4 + quad) * 8];
            }
            #pragma unroll
            for (int nt = 0; nt < 4; ++nt) {
                const int row = wn * 64 + nt * 16 + col;
                bf[nt] = *(const short8*)&Bs[row * 64 + swz8(row, kb * 4 + quad) * 8];
            }
            #pragma unroll
            for (int mt = 0; mt < 4; ++mt)
                #pragma unroll
                for (int nt = 0; nt < 4; ++nt)
                    acc[mt][nt] = __builtin_amdgcn_mfma_f32_16x16x32_bf16(
                        af[mt], bf[nt], acc[mt][nt], 0, 0, 0);
        }
    }
}

// ---------------------------------------------------------------------------
// Fused QKV GEMM; sel==2 (V) writes fragment-swizzled Vp directly.
// ---------------------------------------------------------------------------
__global__ __launch_bounds__(256)
void gemm_qkv(const short* __restrict__ A,
              const short* __restrict__ W0, const short* __restrict__ W1,
              const short* __restrict__ W2,
              const float* __restrict__ b0, const float* __restrict__ b1,
              const float* __restrict__ b2,
              short* __restrict__ Y0, short* __restrict__ Y1,
              short* __restrict__ Vp)
{
    __shared__ __attribute__((aligned(16))) short As[128 * 64];
    __shared__ __attribute__((aligned(16))) short Bs[128 * 64];

    const int sel = blockIdx.x / (DIMN / 128);
    const int nb  = blockIdx.x % (DIMN / 128);
    const short* W    = (sel == 0) ? W0 : (sel == 1) ? W1 : W2;
    const float* bias = (sel == 0) ? b0 : (sel == 1) ? b1 : b2;

    const int tid = threadIdx.x;
    const int wave = tid >> 6, lane = tid & 63;
    const int quad = lane >> 4, col = lane & 15;
    const int wm = wave >> 1, wn = wave & 1;
    const int m0 = blockIdx.y * 128, n0 = nb * 128;

    f32x4 acc[4][4];
    #pragma unroll
    for (int i = 0; i < 4; ++i)
        #pragma unroll
        for (int j = 0; j < 4; ++j)
            #pragma unroll
            for (int r = 0; r < 4; ++r) acc[i][j][r] = 0.f;

    gemm_mainloop(A, W, m0, n0, DIMN, As, Bs, acc);

    if (sel < 2) {
        short* Y = (sel == 0) ? Y0 : Y1;
        #pragma unroll
        for (int mt = 0; mt < 4; ++mt) {
            #pragma unroll
            for (int nt = 0; nt < 4; ++nt) {
                const int n = n0 + wn * 64 + nt * 16 + col;
                const float bb = bias[n];
                #pragma unroll
                for (int r = 0; r < 4; ++r) {
                    const int m = m0 + wm * 64 + mt * 16 + quad * 4 + r;
                    Y[(size_t)m * DIMN + n] = to_bf16(acc[mt][nt][r] + bb);
                }
            }
        }
    } else {
        const int head = nb;
        const int kt64 = blockIdx.y * 2 + wm;
        #pragma unroll
        for (int mt = 0; mt < 4; ++mt) {
            #pragma unroll
            for (int nt = 0; nt < 4; ++nt) {
                const int n = n0 + wn * 64 + nt * 16 + col;
                const float bb = bias[n];
                const int dt = wn * 4 + nt;
                const int chunk = (head * 32 + kt64) * 16 + dt * 2 + (mt >> 1);
                const int off = ((mt & 1) * 2 + (quad >> 1)) * 128 + col * 8 + (quad & 1) * 4;
                short4v o;
                #pragma unroll
                for (int r = 0; r < 4; ++r) o[r] = to_bf16(acc[mt][nt][r] + bb);
                *(short4v*)(Vp + (size_t)chunk * 512 + off) = o;
            }
        }
    }
}

// ---------------------------------------------------------------------------
// Output-projection GEMM, fp32 out.
// ---------------------------------------------------------------------------
__global__ __launch_bounds__(256)
void gemm_out(const short* __restrict__ A, const short* __restrict__ W,
              const float* __restrict__ bias, float* __restrict__ Yf)
{
    __shared__ __attribute__((aligned(16))) short As[128 * 64];
    __shared__ __attribute__((aligned(16))) short Bs[128 * 64];

    const int tid = threadIdx.x;
    const int wave = tid >> 6, lane = tid & 63;
    const int quad = lane >> 4, col = lane & 15;
    const int wm = wave >> 1, wn = wave & 1;
    const int m0 = blockIdx.y * 128, n0 = blockIdx.x * 128;

    f32x4 acc[4][4];
    #pragma unroll
    for (int i = 0; i < 4; ++i)
        #pragma unroll
        for (int j = 0; j < 4; ++j)
            #pragma unroll
            for (int r = 0; r < 4; ++r) acc[i][j][r] = 0.f;

    gemm_mainloop(A, W, m0, n0, DIMN, As, Bs, acc);

    #pragma unroll
    for (int mt = 0; mt < 4; ++mt) {
        #pragma unroll
        for (int nt = 0; nt < 4; ++nt) {
            const int n = n0 + wn * 64 + nt * 16 + col;
            const float bb = bias[n];
            #pragma unroll
            for (int r = 0; r < 4; ++r) {
                const int m = m0 + wm * 64 + mt * 16 + quad * 4 + r;
                Yf[(size_t)m * DIMN + n] = acc[mt][nt][r] + bb;
            }
        }
    }
}

// ---------------------------------------------------------------------------
// Fused RMSNorm + RoPE for Q (grid.y==0, in-place) and K->Kp (grid.y==1).
// Uses __sincosf (hw transcendentals). Q gets 1/sqrt(HD) folded in.
// ---------------------------------------------------------------------------
__global__ __launch_bounds__(256)
void rms_rope_qk(short* __restrict__ qbuf, const short* __restrict__ kbuf,
                 short* __restrict__ Kp,
                 const float* __restrict__ gq, const float* __restrict__ gk,
                 const float* __restrict__ freqs, const int* __restrict__ grid_sizes)
{
    const int s = blockIdx.x;
    const int isK = blockIdx.y;
    const int tid = threadIdx.x;
    short* qrow = qbuf + (size_t)s * DIMN;
    const short* row = isK ? (kbuf + (size_t)s * DIMN) : qrow;
    const float* g = isK ? gk : gq;

    float ss = 0.f;
    if (tid < 192) {
        short8 v = *(const short8*)(row + tid * 8);
        #pragma unroll
        for (int j = 0; j < 8; ++j) { float f = bf_to_f(v[j]); ss += f * f; }
    }
    #pragma unroll
    for (int off = 32; off; off >>= 1) ss += __shfl_down(ss, off, 64);

    __shared__ float red[4];
    __shared__ float s_scale;
    if ((tid & 63) == 0) red[tid >> 6] = ss;
    __syncthreads();
    if (tid == 0) {
        float t = red[0] + red[1] + red[2] + red[3];
        float sc = rsqrtf(t / (float)DIMN + EPSV);
        s_scale = isK ? sc : sc * 0.08838834764831845f;
    }
    __syncthreads();
    const float scale = s_scale;

    const int h = grid_sizes[1], w = grid_sizes[2];
    const int fi = s / (h * w);
    const int hi = (s / w) % h;
    const int wi = s % w;

    if (!isK) {
        for (int p = tid; p < NHEAD * 64; p += 256) {
            const int n = p >> 6;
            const int d = p & 63;
            const int idx = (d < 22) ? fi : ((d < 43) ? hi : wi);
            const float ang = freqs[idx * 64 + d];
            float sn, cs;
            __sincosf(ang, &sn, &cs);
            const int base = n * HDIM + 2 * d;
            const float v0 = bf_to_f(qrow[base]) * scale * g[base];
            const float v1 = bf_to_f(qrow[base + 1]) * scale * g[base + 1];
            qrow[base]     = to_bf16(v0 * cs - v1 * sn);
            qrow[base + 1] = to_bf16(v0 * sn + v1 * cs);
        }
    } else if (tid < 192) {
        const int n = tid >> 4;
        const int o = tid & 15;
        short8 outv;
        #pragma unroll
        for (int pp = 0; pp < 4; ++pp) {
            const int pd = o * 4 + pp;
            const int idx = (pd < 22) ? fi : ((pd < 43) ? hi : wi);
            const float ang = freqs[idx * 64 + pd];
            float sn, cs;
            __sincosf(ang, &sn, &cs);
            const int base = n * HDIM + 2 * pd;
            const float v0 = bf_to_f(row[base]) * scale * g[base];
            const float v1 = bf_to_f(row[base + 1]) * scale * g[base + 1];
            outv[pp * 2]     = to_bf16(v0 * cs - v1 * sn);
            outv[pp * 2 + 1] = to_bf16(v0 * sn + v1 * cs);
        }
        const int kb = s >> 4, colk = s & 15;
        const int kc = o >> 2, quadk = o & 3;
        const size_t addr = ((((size_t)(n * 128 + kb) * 4 + kc) * 64) + quadk * 16 + colk) * 8;
        *(short8*)(Kp + addr) = outv;
    }
}

// ---------------------------------------------------------------------------
// MFMA flash attention — R8/R10 loop body unchanged (measured best).
// NEW: sequential single-buffer epilogue combine (waves 3->2->1 accumulate
// into one fp32 Oc, wave 0 finishes). LDS 25.6 KB -> 9.3 KB so the wave-slot
// cap (8 blocks/CU), not LDS, is the residency limit; grid 6 blocks/CU can
// be fully co-resident.
// ---------------------------------------------------------------------------
__global__ __launch_bounds__(256)
void attn_mfma4(const short* __restrict__ Q, const short* __restrict__ Kp,
                const short* __restrict__ Vp, short* __restrict__ O,
                const int* __restrict__ seq_lens)
{
    // union: loop Ps[4][16*72] shorts = 9216 B; epilogue Oc[16*132] f32 (8448)
    // + Lc[16] f32 (64) = 8512 B.
    __shared__ __attribute__((aligned(16))) char smem[9216];
    short* Ps = (short*)smem;
    float* Oc = (float*)smem;                 // [16][132]
    float* Lc = (float*)(smem + 16 * 132 * 4);

    const int tid = threadIdx.x;
    const int wave = tid >> 6, lane = tid & 63;
    const int quad = lane >> 4, col = lane & 15;
    const int head = blockIdx.y;
    const int row0 = blockIdx.x * 16;
    const int slen = seq_lens[0];
    short* psw = Ps + wave * (16 * 72);

    short8 qf[4];
    #pragma unroll
    for (int kc = 0; kc < 4; ++kc)
        qf[kc] = *(const short8*)(Q + (size_t)(row0 + col) * DIMN
                                  + head * HDIM + kc * 32 + quad * 8);

    f32x4 oacc[8];
    #pragma unroll
    for (int dt = 0; dt < 8; ++dt)
        #pragma unroll
        for (int r = 0; r < 4; ++r) oacc[dt][r] = 0.f;
    float lsum[4] = {0.f, 0.f, 0.f, 0.f};

    const int kbeg = wave * (SLEN / 4);
    for (int kt = kbeg; kt < kbeg + SLEN / 4; kt += 64) {
        f32x4 s[4];
        #pragma unroll
        for (int nt = 0; nt < 4; ++nt)
            #pragma unroll
            for (int r = 0; r < 4; ++r) s[nt][r] = 0.f;

        const int kb0 = kt >> 4;
        #pragma unroll
        for (int kc = 0; kc < 4; ++kc) {
            short8 kf[4];
            #pragma unroll
            for (int nt = 0; nt < 4; ++nt)
                kf[nt] = *(const short8*)(Kp +
                    ((((size_t)(head * 128 + kb0 + nt) * 4 + kc) * 64) + lane) * 8);
            #pragma unroll
            for (int nt = 0; nt < 4; ++nt)
                s[nt] = __builtin_amdgcn_mfma_f32_16x16x32_bf16(qf[kc], kf[nt], s[nt], 0, 0, 0);
        }

        #pragma unroll
        for (int nt = 0; nt < 4; ++nt) {
            const bool masked = (kt + nt * 16 + col >= slen);
            #pragma unroll
            for (int r = 0; r < 4; ++r) {
                float p = masked ? 0.f : __expf(s[nt][r]);
                lsum[r] += p;
                psw[(quad * 4 + r) * 72 + nt * 16 + col] = to_bf16(p);
            }
        }

        short8 pf[2];
        #pragma unroll
        for (int kc = 0; kc < 2; ++kc)
            pf[kc] = *(const short8*)&psw[col * 72 + kc * 32 + quad * 8];

        const size_t vbase = ((size_t)(head * 32 + (kt >> 6)) * 16) * 512;
        #pragma unroll
        for (int dt = 0; dt < 8; ++dt) {
            short8 vf[2];
            #pragma unroll
            for (int kc = 0; kc < 2; ++kc)
                vf[kc] = *(const short8*)(Vp + vbase + ((size_t)(dt * 2 + kc) * 64 + lane) * 8);
            #pragma unroll
            for (int kc = 0; kc < 2; ++kc)
                oacc[dt] = __builtin_amdgcn_mfma_f32_16x16x32_bf16(pf[kc], vf[kc], oacc[dt], 0, 0, 0);
        }
    }

    #pragma unroll
    for (int r = 0; r < 4; ++r) {
        #pragma unroll
        for (int off = 8; off; off >>= 1) lsum[r] += __shfl_xor(lsum[r], off, 64);
    }

    // ---- sequential single-buffer combine: waves 3,2,1 accumulate, 0 ends ----
    __syncthreads();                 // Ps dead; Oc region reusable
    if (wave == 3) {
        #pragma unroll
        for (int dt = 0; dt < 8; ++dt)
            #pragma unroll
            for (int r = 0; r < 4; ++r)
                Oc[(quad * 4 + r) * 132 + dt * 16 + col] = oacc[dt][r];
        if (col == 0) {
            #pragma unroll
            for (int r = 0; r < 4; ++r) Lc[quad * 4 + r] = lsum[r];
        }
    }
    __syncthreads();
    if (wave == 2) {
        #pragma unroll
        for (int dt = 0; dt < 8; ++dt)
            #pragma unroll
            for (int r = 0; r < 4; ++r)
                Oc[(quad * 4 + r) * 132 + dt * 16 + col] += oacc[dt][r];
        if (col == 0) {
            #pragma unroll
            for (int r = 0; r < 4; ++r) Lc[quad * 4 + r] += lsum[r];
        }
    }
    __syncthreads();
    if (wave == 1) {
        #pragma unroll
        for (int dt = 0; dt < 8; ++dt)
            #pragma unroll
            for (int r = 0; r < 4; ++r)
                Oc[(quad * 4 + r) * 132 + dt * 16 + col] += oacc[dt][r];
        if (col == 0) {
            #pragma unroll
            for (int r = 0; r < 4; ++r) Lc[quad * 4 + r] += lsum[r];
        }
    }
    __syncthreads();
    if (wave == 0) {
        float inv[4];
        #pragma unroll
        for (int r = 0; r < 4; ++r)
            inv[r] = 1.0f / (lsum[r] + Lc[quad * 4 + r]);
        #pragma unroll
        for (int dt = 0; dt < 8; ++dt) {
            #pragma unroll
            for (int r = 0; r < 4; ++r) {
                const float v = oacc[dt][r] + Oc[(quad * 4 + r) * 132 + dt * 16 + col];
                O[(size_t)(row0 + quad * 4 + r) * DIMN + head * HDIM + dt * 16 + col]
                    = to_bf16(v * inv[r]);
            }
        }
    }
}

// ---------------------------------------------------------------------------
extern "C" void kernel_launch(void* const* d_in, const int* in_sizes, int n_in,
                              void* d_out, int out_size, void* d_ws, size_t ws_size,
                              hipStream_t stream)
{
    const float* x     = (const float*)d_in[0];
    const float* freqs = (const float*)d_in[1];
    const float* wq    = (const float*)d_in[2];
    const float* bq    = (const float*)d_in[3];
    const float* wk    = (const float*)d_in[4];
    const float* bk    = (const float*)d_in[5];
    const float* wv    = (const float*)d_in[6];
    const float* bv    = (const float*)d_in[7];
    const float* wo    = (const float*)d_in[8];
    const float* bo    = (const float*)d_in[9];
    const float* gq    = (const float*)d_in[10];
    const float* gk    = (const float*)d_in[11];
    const int* seq_lens   = (const int*)d_in[12];
    const int* grid_sizes = (const int*)d_in[13];
    float* out = (float*)d_out;

    const size_t NX = (size_t)SLEN * DIMN;
    const size_t NW = (size_t)DIMN * DIMN;
    short* xb  = (short*)d_ws;
    short* wqb = xb + NX;
    short* wkb = wqb + NW;
    short* wvb = wkb + NW;
    short* wob = wvb + NW;
    short* qb  = wob + NW;
    short* kb  = qb + NX;
    short* vp  = kb + NX;
    short* kp  = vp + NX;
    short* ob  = kp + NX;

    cast5<<<dim3(1536, 5), 256, 0, stream>>>(x, wq, wk, wv, wo,
                                             xb, wqb, wkb, wvb, wob,
                                             (int)NX, (int)NW);

    gemm_qkv<<<dim3(3 * DIMN / 128, SLEN / 128), 256, 0, stream>>>(
        xb, wqb, wkb, wvb, bq, bk, bv, qb, kb, vp);

    rms_rope_qk<<<dim3(SLEN, 2), 256, 0, stream>>>(qb, kb, kp, gq, gk, freqs, grid_sizes);

    attn_mfma4<<<dim3(SLEN / 16, NHEAD), 256, 0, stream>>>(qb, kp, vp, ob, seq_lens);

    gemm_out<<<dim3(DIMN / 128, SLEN / 128), 256, 0, stream>>>(ob, wob, bo, out);
}

// Round 12
// 272.494 us; speedup vs baseline: 1.0420x; 1.0420x over previous
//
#include <hip/hip_runtime.h>
#include <math.h>

#define DIMN 1536
#define NHEAD 12
#define HDIM 128
#define SLEN 2048
#define EPSV 1e-6f

typedef __attribute__((ext_vector_type(8))) short short8;
typedef __attribute__((ext_vector_type(4))) short short4v;
typedef __attribute__((ext_vector_type(4))) float f32x4;

typedef __attribute__((address_space(1))) const void gvoid_t;
typedef __attribute__((address_space(3))) void lvoid_t;

__device__ __forceinline__ void gload_lds16(const void* g, void* l) {
    __builtin_amdgcn_global_load_lds((gvoid_t*)g, (lvoid_t*)l, 16, 0, 0);
}

__device__ inline short to_bf16(float f) {
    union { float f; unsigned u; } v; v.f = f;
    unsigned r = (v.u + 0x7FFFu + ((v.u >> 16) & 1u)) >> 16;
    return (short)r;
}
__device__ inline float bf_to_f(short h) {
    union { unsigned u; float f; } v;
    v.u = ((unsigned)(unsigned short)h) << 16;
    return v.f;
}

// 8-chunk XOR swizzle for the GEMM LDS tiles.
__device__ __forceinline__ int swz8(int row, int c) {
    return c ^ (row & 7);
}

// ---------------------------------------------------------------------------
// Cast 5 fp32 tensors to bf16 (x + 4 weights), one launch.
// ---------------------------------------------------------------------------
__global__ __launch_bounds__(256)
void cast5(const float* s0, const float* s1, const float* s2,
           const float* s3, const float* s4,
           short* d0, short* d1, short* d2, short* d3, short* d4,
           int n0, int nw)
{
    const float* s; short* d; int n;
    switch (blockIdx.y) {
        case 0: s = s0; d = d0; n = n0; break;
        case 1: s = s1; d = d1; n = nw; break;
        case 2: s = s2; d = d2; n = nw; break;
        case 3: s = s3; d = d3; n = nw; break;
        default: s = s4; d = d4; n = nw; break;
    }
    int idx = (blockIdx.x * 256 + threadIdx.x) * 8;
    if (idx >= n) return;
    float4 a = *(const float4*)(s + idx);
    float4 b = *(const float4*)(s + idx + 4);
    short8 r;
    r[0] = to_bf16(a.x); r[1] = to_bf16(a.y); r[2] = to_bf16(a.z); r[3] = to_bf16(a.w);
    r[4] = to_bf16(b.x); r[5] = to_bf16(b.y); r[6] = to_bf16(b.z); r[7] = to_bf16(b.w);
    *(short8*)(d + idx) = r;
}

// ---------------------------------------------------------------------------
// BK=64 MFMA GEMM core (unchanged from R10 best).
// ---------------------------------------------------------------------------
__device__ __forceinline__ void gemm_mainloop(const short* __restrict__ A,
    const short* __restrict__ W, int m0, int n0, int K,
    short* As, short* Bs, f32x4 (&acc)[4][4])
{
    const int tid = threadIdx.x;
    const int wave = tid >> 6, lane = tid & 63;
    const int quad = lane >> 4, col = lane & 15;
    const int wm = wave >> 1, wn = wave & 1;
    const int sr = tid >> 3;
    const int sc = tid & 7;

    for (int kt = 0; kt < K; kt += 64) {
        __syncthreads();
        #pragma unroll
        for (int i = 0; i < 4; ++i) {
            const int row = i * 32 + sr;
            const int c = swz8(row, sc);
            gload_lds16(A + (size_t)(m0 + row) * K + kt + c * 8, As + i * 2048 + tid * 8);
        }
        #pragma unroll
        for (int i = 0; i < 4; ++i) {
            const int row = i * 32 + sr;
            const int c = swz8(row, sc);
            gload_lds16(W + (size_t)(n0 + row) * K + kt + c * 8, Bs + i * 2048 + tid * 8);
        }
        __syncthreads();

        #pragma unroll
        for (int kb = 0; kb < 2; ++kb) {
            short8 af[4], bf[4];
            #pragma unroll
            for (int mt = 0; mt < 4; ++mt) {
                const int row = wm * 64 + mt * 16 + col;
                af[mt] = *(const short8*)&As[row * 64 + swz8(row, kb * 4 + quad) * 8];
            }
            #pragma unroll
            for (int nt = 0; nt < 4; ++nt) {
                const int row = wn * 64 + nt * 16 + col;
                bf[nt] = *(const short8*)&Bs[row * 64 + swz8(row, kb * 4 + quad) * 8];
            }
            #pragma unroll
            for (int mt = 0; mt < 4; ++mt)
                #pragma unroll
                for (int nt = 0; nt < 4; ++nt)
                    acc[mt][nt] = __builtin_amdgcn_mfma_f32_16x16x32_bf16(
                        af[mt], bf[nt], acc[mt][nt], 0, 0, 0);
        }
    }
}

// ---------------------------------------------------------------------------
// Fused QKV GEMM; sel==2 (V) writes fragment-swizzled Vp directly.
// ---------------------------------------------------------------------------
__global__ __launch_bounds__(256)
void gemm_qkv(const short* __restrict__ A,
              const short* __restrict__ W0, const short* __restrict__ W1,
              const short* __restrict__ W2,
              const float* __restrict__ b0, const float* __restrict__ b1,
              const float* __restrict__ b2,
              short* __restrict__ Y0, short* __restrict__ Y1,
              short* __restrict__ Vp)
{
    __shared__ __attribute__((aligned(16))) short As[128 * 64];
    __shared__ __attribute__((aligned(16))) short Bs[128 * 64];

    const int sel = blockIdx.x / (DIMN / 128);
    const int nb  = blockIdx.x % (DIMN / 128);
    const short* W    = (sel == 0) ? W0 : (sel == 1) ? W1 : W2;
    const float* bias = (sel == 0) ? b0 : (sel == 1) ? b1 : b2;

    const int tid = threadIdx.x;
    const int wave = tid >> 6, lane = tid & 63;
    const int quad = lane >> 4, col = lane & 15;
    const int wm = wave >> 1, wn = wave & 1;
    const int m0 = blockIdx.y * 128, n0 = nb * 128;

    f32x4 acc[4][4];
    #pragma unroll
    for (int i = 0; i < 4; ++i)
        #pragma unroll
        for (int j = 0; j < 4; ++j)
            #pragma unroll
            for (int r = 0; r < 4; ++r) acc[i][j][r] = 0.f;

    gemm_mainloop(A, W, m0, n0, DIMN, As, Bs, acc);

    if (sel < 2) {
        short* Y = (sel == 0) ? Y0 : Y1;
        #pragma unroll
        for (int mt = 0; mt < 4; ++mt) {
            #pragma unroll
            for (int nt = 0; nt < 4; ++nt) {
                const int n = n0 + wn * 64 + nt * 16 + col;
                const float bb = bias[n];
                #pragma unroll
                for (int r = 0; r < 4; ++r) {
                    const int m = m0 + wm * 64 + mt * 16 + quad * 4 + r;
                    Y[(size_t)m * DIMN + n] = to_bf16(acc[mt][nt][r] + bb);
                }
            }
        }
    } else {
        const int head = nb;
        const int kt64 = blockIdx.y * 2 + wm;
        #pragma unroll
        for (int mt = 0; mt < 4; ++mt) {
            #pragma unroll
            for (int nt = 0; nt < 4; ++nt) {
                const int n = n0 + wn * 64 + nt * 16 + col;
                const float bb = bias[n];
                const int dt = wn * 4 + nt;
                const int chunk = (head * 32 + kt64) * 16 + dt * 2 + (mt >> 1);
                const int off = ((mt & 1) * 2 + (quad >> 1)) * 128 + col * 8 + (quad & 1) * 4;
                short4v o;
                #pragma unroll
                for (int r = 0; r < 4; ++r) o[r] = to_bf16(acc[mt][nt][r] + bb);
                *(short4v*)(Vp + (size_t)chunk * 512 + off) = o;
            }
        }
    }
}

// ---------------------------------------------------------------------------
// Output-projection GEMM, fp32 out.
// ---------------------------------------------------------------------------
__global__ __launch_bounds__(256)
void gemm_out(const short* __restrict__ A, const short* __restrict__ W,
              const float* __restrict__ bias, float* __restrict__ Yf)
{
    __shared__ __attribute__((aligned(16))) short As[128 * 64];
    __shared__ __attribute__((aligned(16))) short Bs[128 * 64];

    const int tid = threadIdx.x;
    const int wave = tid >> 6, lane = tid & 63;
    const int quad = lane >> 4, col = lane & 15;
    const int wm = wave >> 1, wn = wave & 1;
    const int m0 = blockIdx.y * 128, n0 = blockIdx.x * 128;

    f32x4 acc[4][4];
    #pragma unroll
    for (int i = 0; i < 4; ++i)
        #pragma unroll
        for (int j = 0; j < 4; ++j)
            #pragma unroll
            for (int r = 0; r < 4; ++r) acc[i][j][r] = 0.f;

    gemm_mainloop(A, W, m0, n0, DIMN, As, Bs, acc);

    #pragma unroll
    for (int mt = 0; mt < 4; ++mt) {
        #pragma unroll
        for (int nt = 0; nt < 4; ++nt) {
            const int n = n0 + wn * 64 + nt * 16 + col;
            const float bb = bias[n];
            #pragma unroll
            for (int r = 0; r < 4; ++r) {
                const int m = m0 + wm * 64 + mt * 16 + quad * 4 + r;
                Yf[(size_t)m * DIMN + n] = acc[mt][nt][r] + bb;
            }
        }
    }
}

// ---------------------------------------------------------------------------
// Fused RMSNorm + RoPE for Q (grid.y==0, in-place) and K->Kp (grid.y==1).
// ---------------------------------------------------------------------------
__global__ __launch_bounds__(256)
void rms_rope_qk(short* __restrict__ qbuf, const short* __restrict__ kbuf,
                 short* __restrict__ Kp,
                 const float* __restrict__ gq, const float* __restrict__ gk,
                 const float* __restrict__ freqs, const int* __restrict__ grid_sizes)
{
    const int s = blockIdx.x;
    const int isK = blockIdx.y;
    const int tid = threadIdx.x;
    short* qrow = qbuf + (size_t)s * DIMN;
    const short* row = isK ? (kbuf + (size_t)s * DIMN) : qrow;
    const float* g = isK ? gk : gq;

    float ss = 0.f;
    if (tid < 192) {
        short8 v = *(const short8*)(row + tid * 8);
        #pragma unroll
        for (int j = 0; j < 8; ++j) { float f = bf_to_f(v[j]); ss += f * f; }
    }
    #pragma unroll
    for (int off = 32; off; off >>= 1) ss += __shfl_down(ss, off, 64);

    __shared__ float red[4];
    __shared__ float s_scale;
    if ((tid & 63) == 0) red[tid >> 6] = ss;
    __syncthreads();
    if (tid == 0) {
        float t = red[0] + red[1] + red[2] + red[3];
        float sc = rsqrtf(t / (float)DIMN + EPSV);
        s_scale = isK ? sc : sc * 0.08838834764831845f;
    }
    __syncthreads();
    const float scale = s_scale;

    const int h = grid_sizes[1], w = grid_sizes[2];
    const int fi = s / (h * w);
    const int hi = (s / w) % h;
    const int wi = s % w;

    if (!isK) {
        for (int p = tid; p < NHEAD * 64; p += 256) {
            const int n = p >> 6;
            const int d = p & 63;
            const int idx = (d < 22) ? fi : ((d < 43) ? hi : wi);
            const float ang = freqs[idx * 64 + d];
            float sn, cs;
            __sincosf(ang, &sn, &cs);
            const int base = n * HDIM + 2 * d;
            const float v0 = bf_to_f(qrow[base]) * scale * g[base];
            const float v1 = bf_to_f(qrow[base + 1]) * scale * g[base + 1];
            qrow[base]     = to_bf16(v0 * cs - v1 * sn);
            qrow[base + 1] = to_bf16(v0 * sn + v1 * cs);
        }
    } else if (tid < 192) {
        const int n = tid >> 4;
        const int o = tid & 15;
        short8 outv;
        #pragma unroll
        for (int pp = 0; pp < 4; ++pp) {
            const int pd = o * 4 + pp;
            const int idx = (pd < 22) ? fi : ((pd < 43) ? hi : wi);
            const float ang = freqs[idx * 64 + pd];
            float sn, cs;
            __sincosf(ang, &sn, &cs);
            const int base = n * HDIM + 2 * pd;
            const float v0 = bf_to_f(row[base]) * scale * g[base];
            const float v1 = bf_to_f(row[base + 1]) * scale * g[base + 1];
            outv[pp * 2]     = to_bf16(v0 * cs - v1 * sn);
            outv[pp * 2 + 1] = to_bf16(v0 * sn + v1 * cs);
        }
        const int kb = s >> 4, colk = s & 15;
        const int kc = o >> 2, quadk = o & 3;
        const size_t addr = ((((size_t)(n * 128 + kb) * 4 + kc) * 64) + quadk * 16 + colk) * 8;
        *(short8*)(Kp + addr) = outv;
    }
}

// ---------------------------------------------------------------------------
// MFMA flash attention v6 — LDS-shared K/V streaming.
// Block = 128 threads (2 waves), 32 q-rows (16 per wave), NO key split:
// both waves walk all 32 key-steps; each step's K-tile (16 KB) + V-tile
// (16 KB) staged once into LDS via global_load_lds and fragment-read by both
// waves. Halves the per-output K/V L2 traffic (1.5 GB -> 786 MB) vs the
// key-split design. Each wave owns complete rows -> no combine epilogue.
// Max-free softmax as before. LDS = 32 KB stage + 4.6 KB P = 36.6 KB.
// Grid 768 blocks = exactly 3 blocks/CU.
// ---------------------------------------------------------------------------
__global__ __launch_bounds__(128)
void attn_mfma6(const short* __restrict__ Q, const short* __restrict__ Kp,
                const short* __restrict__ Vp, short* __restrict__ O,
                const int* __restrict__ seq_lens)
{
    __shared__ __attribute__((aligned(16))) char smem[32768 + 2 * 16 * 72 * 2];
    short* KL = (short*)smem;                  // 16 KB: 16 chunks x 512 elems
    short* VL = (short*)(smem + 16384);        // 16 KB
    short* Ps = (short*)(smem + 32768);        // 2 waves x 16 x 72

    const int tid = threadIdx.x;
    const int wave = tid >> 6, lane = tid & 63;
    const int quad = lane >> 4, col = lane & 15;
    const int head = blockIdx.y;
    const int row0 = blockIdx.x * 32 + wave * 16;
    const int slen = seq_lens[0];
    short* psw = Ps + wave * (16 * 72);

    short8 qf[4];
    #pragma unroll
    for (int kc = 0; kc < 4; ++kc)
        qf[kc] = *(const short8*)(Q + (size_t)(row0 + col) * DIMN
                                  + head * HDIM + kc * 32 + quad * 8);

    f32x4 oacc[8];
    #pragma unroll
    for (int dt = 0; dt < 8; ++dt)
        #pragma unroll
        for (int r = 0; r < 4; ++r) oacc[dt][r] = 0.f;
    float lsum[4] = {0.f, 0.f, 0.f, 0.f};

    for (int kt64 = 0; kt64 < SLEN / 64; ++kt64) {
        __syncthreads();   // previous step's LDS reads complete
        {
            // K chunks for (head, kb=kt64*4..+3, kc=0..3) are 16 KB contiguous;
            // V chunks for (head, kt64) are 16 KB contiguous.
            const char* ks = (const char*)Kp + ((size_t)(head * 128 + kt64 * 4) * 4) * 1024;
            const char* vs = (const char*)Vp + ((size_t)(head * 32 + kt64) * 16) * 1024;
            #pragma unroll
            for (int i = 0; i < 8; ++i)
                gload_lds16(ks + i * 2048 + tid * 16, smem + i * 2048 + tid * 16);
            #pragma unroll
            for (int i = 0; i < 8; ++i)
                gload_lds16(vs + i * 2048 + tid * 16, smem + 16384 + i * 2048 + tid * 16);
        }
        __syncthreads();   // staging visible (vmcnt drained by barrier)

        // ---- S = Q K^T (16 rows x 64 keys), K frags from LDS ----
        f32x4 s[4];
        #pragma unroll
        for (int nt = 0; nt < 4; ++nt)
            #pragma unroll
            for (int r = 0; r < 4; ++r) s[nt][r] = 0.f;

        #pragma unroll
        for (int kc = 0; kc < 4; ++kc) {
            short8 kf[4];
            #pragma unroll
            for (int nt = 0; nt < 4; ++nt)
                kf[nt] = *(const short8*)&KL[(nt * 4 + kc) * 512 + lane * 8];
            #pragma unroll
            for (int nt = 0; nt < 4; ++nt)
                s[nt] = __builtin_amdgcn_mfma_f32_16x16x32_bf16(qf[kc], kf[nt], s[nt], 0, 0, 0);
        }

        // ---- mask + exp (no max) + l accumulation + P store ----
        const int kt = kt64 * 64;
        #pragma unroll
        for (int nt = 0; nt < 4; ++nt) {
            const bool masked = (kt + nt * 16 + col >= slen);
            #pragma unroll
            for (int r = 0; r < 4; ++r) {
                float p = masked ? 0.f : __expf(s[nt][r]);
                lsum[r] += p;
                psw[(quad * 4 + r) * 72 + nt * 16 + col] = to_bf16(p);
            }
        }

        short8 pf[2];
        #pragma unroll
        for (int kc = 0; kc < 2; ++kc)
            pf[kc] = *(const short8*)&psw[col * 72 + kc * 32 + quad * 8];

        // ---- PV: V frags from LDS ----
        #pragma unroll
        for (int dt = 0; dt < 8; ++dt) {
            short8 vf[2];
            #pragma unroll
            for (int kc = 0; kc < 2; ++kc)
                vf[kc] = *(const short8*)&VL[(dt * 2 + kc) * 512 + lane * 8];
            #pragma unroll
            for (int kc = 0; kc < 2; ++kc)
                oacc[dt] = __builtin_amdgcn_mfma_f32_16x16x32_bf16(pf[kc], vf[kc], oacc[dt], 0, 0, 0);
        }
    }

    // ---- epilogue: per-wave row sums, direct store (no combine needed) ----
    float inv[4];
    #pragma unroll
    for (int r = 0; r < 4; ++r) {
        #pragma unroll
        for (int off = 8; off; off >>= 1) lsum[r] += __shfl_xor(lsum[r], off, 64);
        inv[r] = 1.0f / lsum[r];
    }
    #pragma unroll
    for (int dt = 0; dt < 8; ++dt) {
        #pragma unroll
        for (int r = 0; r < 4; ++r) {
            O[(size_t)(row0 + quad * 4 + r) * DIMN + head * HDIM + dt * 16 + col]
                = to_bf16(oacc[dt][r] * inv[r]);
        }
    }
}

// ---------------------------------------------------------------------------
extern "C" void kernel_launch(void* const* d_in, const int* in_sizes, int n_in,
                              void* d_out, int out_size, void* d_ws, size_t ws_size,
                              hipStream_t stream)
{
    const float* x     = (const float*)d_in[0];
    const float* freqs = (const float*)d_in[1];
    const float* wq    = (const float*)d_in[2];
    const float* bq    = (const float*)d_in[3];
    const float* wk    = (const float*)d_in[4];
    const float* bk    = (const float*)d_in[5];
    const float* wv    = (const float*)d_in[6];
    const float* bv    = (const float*)d_in[7];
    const float* wo    = (const float*)d_in[8];
    const float* bo    = (const float*)d_in[9];
    const float* gq    = (const float*)d_in[10];
    const float* gk    = (const float*)d_in[11];
    const int* seq_lens   = (const int*)d_in[12];
    const int* grid_sizes = (const int*)d_in[13];
    float* out = (float*)d_out;

    const size_t NX = (size_t)SLEN * DIMN;
    const size_t NW = (size_t)DIMN * DIMN;
    short* xb  = (short*)d_ws;
    short* wqb = xb + NX;
    short* wkb = wqb + NW;
    short* wvb = wkb + NW;
    short* wob = wvb + NW;
    short* qb  = wob + NW;
    short* kb  = qb + NX;
    short* vp  = kb + NX;
    short* kp  = vp + NX;
    short* ob  = kp + NX;

    cast5<<<dim3(1536, 5), 256, 0, stream>>>(x, wq, wk, wv, wo,
                                             xb, wqb, wkb, wvb, wob,
                                             (int)NX, (int)NW);

    gemm_qkv<<<dim3(3 * DIMN / 128, SLEN / 128), 256, 0, stream>>>(
        xb, wqb, wkb, wvb, bq, bk, bv, qb, kb, vp);

    rms_rope_qk<<<dim3(SLEN, 2), 256, 0, stream>>>(qb, kb, kp, gq, gk, freqs, grid_sizes);

    attn_mfma6<<<dim3(SLEN / 32, NHEAD), 128, 0, stream>>>(qb, kp, vp, ob, seq_lens);

    gemm_out<<<dim3(DIMN / 128, SLEN / 128), 256, 0, stream>>>(ob, wob, bo, out);
}